// Round 10
// baseline (265.435 us; speedup 1.0000x reference)
//
#include <hip/hip_runtime.h>

#define NN 50000
#define EE 800000
#define MM 3
#define HH 2
#define IND 128
#define HIDD 64
#define HEADD 32
#define OUTD 16
#define ATTD 128

#define NBKT 64
#define BSZ 782

#define NG4 200000
#define BBLK 196
#define QCAP 13200

#define GLS 136            // ggl LDS row stride (u16); zl overlays as float stride 68
#define XWN 50048          // xw rows per metapath incl. zero pad rows [NN, XWN)
#define GBR 32             // k_gpost rows (dsts) per block (256 thr / 4 waves)

typedef unsigned char u8;
typedef unsigned short u16;
typedef unsigned long long u64;
typedef short bf16x8 __attribute__((ext_vector_type(8)));
typedef unsigned short u16x8 __attribute__((ext_vector_type(8)));
typedef u64 u64x2 __attribute__((ext_vector_type(2)));
typedef unsigned int u32x4 __attribute__((ext_vector_type(4)));
typedef float f32x2 __attribute__((ext_vector_type(2)));
typedef float f32x4 __attribute__((ext_vector_type(4)));

__device__ __forceinline__ float lrelu(float v) { return v > 0.f ? v : 0.1f * v; }

__device__ __forceinline__ float fast_tanh(float x) {
    float ax = fabsf(x);
    float e = __expf(-2.0f * ax);
    float t = (1.0f - e) * __builtin_amdgcn_rcpf(1.0f + e);
    return copysignf(t, x);
}

__device__ __forceinline__ u16 f2b(float f) {          // fp32 -> bf16 RNE
    union { float f; unsigned int u; } v; v.f = f;
    unsigned int r = v.u + 0x7fffu + ((v.u >> 16) & 1u);
    return (u16)(r >> 16);
}
__device__ __forceinline__ float b2f(u16 u) {
    union { unsigned int u; float f; } v; v.u = ((unsigned int)u) << 16; return v.f;
}

__device__ __forceinline__ u8 f2e4hw(float f) {
    int r = __builtin_amdgcn_cvt_pk_fp8_f32(f, f, 0, false);
    return (u8)(r & 0xff);
}

// decode 16 fp8 bytes into 8 f32x2 partial accumulators via hw cvt
__device__ __forceinline__ void acc16(f32x2* acc, u32x4 w) {
#pragma unroll
    for (int i = 0; i < 4; i++) {
        acc[2 * i]     += __builtin_amdgcn_cvt_pk_f32_fp8(w[i], false);
        acc[2 * i + 1] += __builtin_amdgcn_cvt_pk_f32_fp8(w[i], true);
    }
}

// ================= phase A: bucket edges into 64 fine dst-buckets =================
__global__ __launch_bounds__(256) void k_bucket(const int* __restrict__ ei,
                                                u64* __restrict__ queues,
                                                int* __restrict__ gcur) {
    __shared__ int cnt[NBKT];
    __shared__ int base[NBKT];
    const int m = blockIdx.y, tid = threadIdx.x;
    const int4* s4 = (const int4*)(ei + (size_t)m * 2 * EE);
    const int4* d4 = (const int4*)(ei + (size_t)m * 2 * EE + EE);
    const int q0 = blockIdx.x * 1024;
    if (tid < NBKT) cnt[tid] = 0;
    __syncthreads();
#pragma unroll
    for (int i = 0; i < 4; i++) {
        int q = q0 + i * 256 + tid;
        if (q < NG4) {
            int4 v = d4[q];
            atomicAdd(&cnt[v.x / BSZ], 1);
            atomicAdd(&cnt[v.y / BSZ], 1);
            atomicAdd(&cnt[v.z / BSZ], 1);
            atomicAdd(&cnt[v.w / BSZ], 1);
        }
    }
    __syncthreads();
    if (tid < NBKT) { base[tid] = atomicAdd(&gcur[m * NBKT + tid], cnt[tid]); cnt[tid] = 0; }
    __syncthreads();
#pragma unroll
    for (int i = 0; i < 4; i++) {
        int q = q0 + i * 256 + tid;
        if (q < NG4) {
            int4 dv = d4[q];
            int4 sv = s4[q];
            int ds[4] = {dv.x, dv.y, dv.z, dv.w};
            int ss[4] = {sv.x, sv.y, sv.z, sv.w};
#pragma unroll
            for (int e = 0; e < 4; e++) {
                int b = ds[e] / BSZ;
                int slot = base[b] + atomicAdd(&cnt[b], 1);
                if (slot < QCAP) {
                    u64 pk = ((u64)(unsigned)ds[e] << 32) | (unsigned)ss[e];
                    queues[((size_t)(m * NBKT + b)) * QCAP + slot] = pk;
                }
            }
        }
    }
}

// ================= bucket-base scan =================
__global__ void k_pscan(const int* __restrict__ gcur, int* __restrict__ pbase) {
    int t = threadIdx.x;
    if (t < MM) {
        int run = 0;
        for (int b = 0; b < NBKT; b++) {
            int L = gcur[t * NBKT + b]; if (L > QCAP) L = QCAP;
            pbase[t * NBKT + b] = run; run += L;
        }
    }
}

// ================= CSR build: one block owns one (m, bucket) =================
__global__ __launch_bounds__(512) void k_csr(const u64* __restrict__ queues,
                                             const int* __restrict__ gcur,
                                             const int* __restrict__ pbase,
                                             int* __restrict__ ofs,
                                             float* __restrict__ rs,
                                             int* __restrict__ sorted) {
    __shared__ int cnt[BSZ];
    __shared__ int wscan[8];
    const int m = blockIdx.y;
    const int b = blockIdx.x;
    const int tid = threadIdx.x;
    const int lane = tid & 63, w = tid >> 6;
    int qlen = gcur[m * NBKT + b]; if (qlen > QCAP) qlen = QCAP;
    const u64* q = queues + ((size_t)(m * NBKT + b)) * QCAP;
    const u64x2* q2 = (const u64x2*)q;
    const int dlo = b * BSZ;
    const int nd = min(dlo + BSZ, NN) - dlo;
    const int n2 = qlen >> 1;
    for (int i = tid; i < BSZ; i += 512) cnt[i] = 0;
    __syncthreads();
    for (int i = tid; i < n2; i += 512) {
        u64x2 e = q2[i];
        atomicAdd(&cnt[(int)(e.x >> 32) - dlo], 1);
        atomicAdd(&cnt[(int)(e.y >> 32) - dlo], 1);
    }
    if (tid == 0 && (qlen & 1))
        atomicAdd(&cnt[(int)(q[qlen - 1] >> 32) - dlo], 1);
    __syncthreads();
    const int c0 = tid * 2;
    int v0 = (c0 < BSZ) ? cnt[c0] : 0;
    int v1 = (c0 + 1 < BSZ) ? cnt[c0 + 1] : 0;
    int s = v0 + v1;
    int vv = s;
    for (int off = 1; off < 64; off <<= 1) { int t = __shfl_up(vv, off); if (lane >= off) vv += t; }
    if (lane == 63) wscan[w] = vv;
    __syncthreads();
    if (tid == 0) { int run = 0; for (int j = 0; j < 8; j++) { int t = wscan[j]; wscan[j] = run; run += t; } }
    __syncthreads();
    int excl = wscan[w] + vv - s;
    int g0 = pbase[m * NBKT + b] + excl;
    int g1 = g0 + v0;
    if (c0 < nd) {
        ofs[(size_t)m * (NN + 1) + dlo + c0] = g0;
        rs[(size_t)m * NN + dlo + c0] = rsqrtf((float)(v0 + 1));
    }
    if (c0 + 1 < nd) {
        ofs[(size_t)m * (NN + 1) + dlo + c0 + 1] = g1;
        rs[(size_t)m * NN + dlo + c0 + 1] = rsqrtf((float)(v1 + 1));
    }
    if (b == NBKT - 1 && tid == 0)
        ofs[(size_t)m * (NN + 1) + NN] = EE;
    __syncthreads();
    if (c0 < BSZ) cnt[c0] = g0;
    if (c0 + 1 < BSZ) cnt[c0 + 1] = g1;
    __syncthreads();
    int* srt = sorted + (size_t)m * EE;
    for (int i = tid; i < n2; i += 512) {
        u64x2 e = q2[i];
        int p0 = atomicAdd(&cnt[(int)(e.x >> 32) - dlo], 1);
        srt[p0] = (int)(e.x & 0xffffffffu);
        int p1 = atomicAdd(&cnt[(int)(e.y >> 32) - dlo], 1);
        srt[p1] = (int)(e.y & 0xffffffffu);
    }
    if (tid == 0 && (qlen & 1)) {
        u64 e = q[qlen - 1];
        int p0 = atomicAdd(&cnt[(int)(e >> 32) - dlo], 1);
        srt[p0] = (int)(e & 0xffffffffu);
    }
}

// ================= x -> bf16 (once, reused by all 3 metapaths) =================
__global__ __launch_bounds__(256) void k_xcvt(const float* __restrict__ x,
                                              u16* __restrict__ xb) {
    int t = blockIdx.x * 256 + threadIdx.x;          // 8 floats per thread
    if (t < NN * IND / 8) {
        const float4* xp = (const float4*)x + (size_t)t * 2;
        float4 a = xp[0], b = xp[1];
        u16x8 o;
        o[0] = f2b(a.x); o[1] = f2b(a.y); o[2] = f2b(a.z); o[3] = f2b(a.w);
        o[4] = f2b(b.x); o[5] = f2b(b.y); o[6] = f2b(b.z); o[7] = f2b(b.w);
        *(u16x8*)&xb[(size_t)t * 8] = o;
    }
}

// ================= weight prep: fp32 -> bf16 MFMA B-fragment layout =================
__global__ __launch_bounds__(256) void k_prep(const float* __restrict__ We, const float* __restrict__ Wc,
                                              const float* __restrict__ Wd, const float* __restrict__ Ws,
                                              u16* __restrict__ wbe, u16* __restrict__ wbc,
                                              u16* __restrict__ wbd, u16* __restrict__ wbs) {
    int t = blockIdx.x * 256 + threadIdx.x;
    if (t >= 11776) return;
    bf16x8 val;
    u16* dst;
    if (t < 6144) {                       // enc
        int m = t >> 11, r = t & 2047;
        int nt = r >> 8, ks = (r >> 6) & 3, lane = r & 63;
        int n = nt * 16 + (lane & 15), h = n >> 6, o = n & 63;
        int kb = ks * 32 + (lane >> 4) * 8;
        const float* w = We + ((size_t)(m * 2 + h) * 128) * 64;
#pragma unroll
        for (int j = 0; j < 8; j++) val[j] = (short)f2b(w[(size_t)(kb + j) * 64 + o]);
        dst = wbe + ((size_t)m * 2048 + r) * 8;
    } else if (t < 9216) {                // conv
        int u = t - 6144;
        int m = u >> 10, r = u & 1023;
        int nt = r >> 7, ks = (r >> 6) & 1, lane = r & 63;
        int h = nt >> 2, o = (nt & 3) * 16 + (lane & 15);
        int kb = ks * 32 + (lane >> 4) * 8;
        const float* w = Wc + ((size_t)(m * 2 + h) * 64) * 64;
#pragma unroll
        for (int j = 0; j < 8; j++) val[j] = (short)f2b(w[(size_t)(kb + j) * 64 + o]);
        dst = wbc + ((size_t)m * 1024 + r) * 8;
    } else if (t < 10752) {               // dec
        int u = t - 9216;
        int m = u >> 9, r = u & 511;
        int nt = r >> 7, ks = (r >> 6) & 1, lane = r & 63;
        int h = nt >> 1, o = (nt & 1) * 16 + (lane & 15);
        int kb = ks * 32 + (lane >> 4) * 8;
        const float* w = Wd + ((size_t)(m * 2 + h) * 64) * 32;
#pragma unroll
        for (int j = 0; j < 8; j++) val[j] = (short)f2b(w[(size_t)(kb + j) * 32 + o]);
        dst = wbd + ((size_t)m * 512 + r) * 8;
    } else {                              // W_s
        int r = t - 10752;
        int nt = r >> 7, ks = (r >> 6) & 1, lane = r & 63;
        int n = nt * 16 + (lane & 15);
        int kb = ks * 32 + (lane >> 4) * 8;
#pragma unroll
        for (int j = 0; j < 8; j++) val[j] = (short)f2b(Ws[(size_t)(kb + j) * 128 + n]);
        dst = wbs + (size_t)r * 8;
    }
    *(bf16x8*)dst = val;
}

// ================= fused enc+conv (per metapath): xw' = e4m3(64 * rs[row] * (h @ Wc)) =================
#define HLS 133
__global__ __launch_bounds__(256) void k_encconv(const u16* __restrict__ xb,
                                                 const u16* __restrict__ wbe_all,
                                                 const float* __restrict__ be_all,
                                                 const u16* __restrict__ wbc_all,
                                                 const float* __restrict__ rs_all,
                                                 u8* __restrict__ xw_all) {
    __shared__ float hl[64 * HLS];
    const int m = blockIdx.y;
    const int tid = threadIdx.x, lane = tid & 63, wave = tid >> 6;
    const int quad = lane >> 4, c16 = lane & 15;
    const int row = blockIdx.x * 64 + wave * 16 + c16;
    const bool ok = row < NN;
    const bf16x8* wbE = (const bf16x8*)(wbe_all + (size_t)m * 2048 * 8);
    const float* be = be_all + m * 2 * 64;
    const float* rs = rs_all + (size_t)m * NN;
    u8* xw = xw_all + (size_t)m * XWN * 128;
    f32x4 zero = {0.f, 0.f, 0.f, 0.f};
    f32x4 acc[8];
#pragma unroll
    for (int nt = 0; nt < 8; nt++) acc[nt] = zero;
#pragma unroll
    for (int ks = 0; ks < 4; ks++) {
        bf16x8 a = {0, 0, 0, 0, 0, 0, 0, 0};
        if (ok) a = *(const bf16x8*)&xb[(size_t)row * 128 + ks * 32 + quad * 8];
#pragma unroll
        for (int nt = 0; nt < 8; nt++)
            acc[nt] = __builtin_amdgcn_mfma_f32_16x16x32_bf16(a, wbE[(nt * 4 + ks) * 64 + lane], acc[nt], 0, 0, 0);
    }
    const int rbl = wave * 16 + quad * 4;
#pragma unroll
    for (int nt = 0; nt < 8; nt++) {
        int col = nt * 16 + c16, hh = col >> 6, o = col & 63;
        float bias = be[hh * 64 + o];
#pragma unroll
        for (int j = 0; j < 4; j++) {
            int rl = rbl + j;
            int rg = blockIdx.x * 64 + rl;
            hl[rl * HLS + col] = (rg < NN) ? lrelu(acc[nt][j] + bias) : 0.f;
        }
    }
    __syncthreads();
    const bf16x8* wbC = (const bf16x8*)(wbc_all + (size_t)m * 1024 * 8);
    f32x4 cacc[8];
#pragma unroll
    for (int nt = 0; nt < 8; nt++) cacc[nt] = zero;
    const int rl = wave * 16 + c16;
#pragma unroll
    for (int ks = 0; ks < 2; ks++) {
        bf16x8 a0, a1;
        const float* hp = &hl[rl * HLS + ks * 32 + quad * 8];
#pragma unroll
        for (int j = 0; j < 8; j++) { a0[j] = (short)f2b(hp[j]); a1[j] = (short)f2b(hp[64 + j]); }
#pragma unroll
        for (int nt = 0; nt < 8; nt++)
            cacc[nt] = __builtin_amdgcn_mfma_f32_16x16x32_bf16(nt < 4 ? a0 : a1, wbC[(nt * 2 + ks) * 64 + lane], cacc[nt], 0, 0, 0);
    }
    float rsv[4];
#pragma unroll
    for (int j = 0; j < 4; j++) {
        int r = blockIdx.x * 64 + rbl + j;
        rsv[j] = (r < NN) ? rs[r] * 64.f : 0.f;
    }
#pragma unroll
    for (int nt = 0; nt < 8; nt++) {
        int col = nt * 16 + c16;
#pragma unroll
        for (int j = 0; j < 4; j++) {
            int r = blockIdx.x * 64 + rbl + j;
            // rows [NN, XWN) get rsv=0 -> e4m3(0) = 0x00 : zero pad row for gather clamping
            xw[(size_t)r * 128 + col] = f2e4hw(cacc[nt][j] * rsv[j]);
        }
    }
}

// ================= fused gather + post + score (256 thr / 4 waves / 32 dsts) =================
// Smaller blocks: barrier couples 4 waves not 8 (less straggler idle), wave-slot
// limit 8 blocks/CU, LDS 8.7KB -> occupancy ceiling = full 32 waves/CU.
// Gather: R2-proven 2-buffer pipeline (8 rows in flight), shfl idx broadcast.
__global__ __launch_bounds__(256) void k_gpost(const int* __restrict__ sorted_all,
                                               const int* __restrict__ ofs_all,
                                               const float* __restrict__ rs_all,
                                               const u8* __restrict__ xw_all,
                                               const float* __restrict__ bconv_all,
                                               const u16* __restrict__ wbd_all,
                                               const float* __restrict__ bdec_all,
                                               const u16* __restrict__ wbs,
                                               const float* __restrict__ bs,
                                               const float* __restrict__ qv,
                                               u16* __restrict__ z_all,
                                               float* __restrict__ score) {
    __shared__ u16 shm[GBR * GLS];          // ggl (u16) / zl (float, stride 68) overlay
    __shared__ float spart[4];
    u16* ggl = shm;
    float* zl = (float*)shm;
    const int m = blockIdx.y;
    const int tid = threadIdx.x, lane = tid & 63, wave = tid >> 6;   // 4 waves
    const int* sorted = sorted_all + (size_t)m * EE;
    const int* ofs = ofs_all + (size_t)m * (NN + 1);
    const float* rs = rs_all + (size_t)m * NN;
    const u8* xw = xw_all + (size_t)m * XWN * 128;
    const float* bconv = bconv_all + m * 2 * 64;
    const float* bdec = bdec_all + m * 2 * 32;
    u16* z = z_all + (size_t)m * NN * 64;

    // ---- gather ----
    {
        const int g = lane >> 3, c = lane & 7;
        const int wbase = blockIdx.x * GBR + wave * 8;
        const int dst = wbase + g;
        const bool on = dst < NN;
        int ov = 0;
        { int ii = wbase + lane; if (lane < 9) ov = ofs[ii > NN ? NN : ii]; }
        const int beg = __shfl(ov, g);
        const int deg = __shfl(ov, g + 1) - beg;       // 0 for dst >= NN
        int degmax = max(deg, __shfl_xor(deg, 8));
        degmax = max(degmax, __shfl_xor(degmax, 16));
        degmax = max(degmax, __shfl_xor(degmax, 32));  // wave-uniform
        const int coff = c * 16;

        // idx load: lanes (c&3)=k hold index of row j+k (clamped to zero pad row NN)
        auto lidx = [&](int j) -> int {
            int t = j + (c & 3);
            return (t < deg) ? sorted[beg + t] : NN;
        };
        // row loads: broadcast idx within group, each lane loads its 16B slice
        auto lrow = [&](int iv, u32x4* wv) {
#pragma unroll
            for (int k = 0; k < 4; k++) {
                int s = __shfl(iv, (lane & 0x38) + k);
                wv[k] = *(const u32x4*)&xw[(size_t)(unsigned)s * 128 + coff];
            }
        };

        f32x2 acc[8];
#pragma unroll
        for (int i = 0; i < 8; i++) acc[i] = 0.f;

        int i0 = lidx(0);
        int i1 = lidx(4);
        // own row (self-loop): 8 consecutive rows per wave, fully coalesced
        {
            int sd = on ? dst : NN;
            u32x4 w = *(const u32x4*)&xw[(size_t)sd * 128 + coff];
            acc16(acc, w);
        }
        u32x4 wA[4], wB[4];
        lrow(i0, wA);
        const int nch = ((degmax + 7) >> 3) * 2;       // even #chunks of 4 rows
        for (int ch = 0; ch < nch; ch += 2) {
            lrow(i1, wB);                              // issue next chunk's rows
            i0 = lidx(ch * 4 + 8);                     // idx 2 chunks ahead
#pragma unroll
            for (int k = 0; k < 4; k++) acc16(acc, wA[k]);
            lrow(i0, wA);
            i1 = lidx(ch * 4 + 12);
#pragma unroll
            for (int k = 0; k < 4; k++) acc16(acc, wB[k]);
        }

        float rsv = on ? rs[dst] * (1.f / 64.f) : 0.f;
        u16x8 o0, o1;
#pragma unroll
        for (int i = 0; i < 4; i++) {
            o0[2 * i]     = f2b(acc[i].x * rsv);
            o0[2 * i + 1] = f2b(acc[i].y * rsv);
            o1[2 * i]     = f2b(acc[i + 4].x * rsv);
            o1[2 * i + 1] = f2b(acc[i + 4].y * rsv);
        }
        u16* gp = &ggl[(wave * 8 + g) * GLS + coff];
        *(u16x8*)gp = o0;
        *(u16x8*)(gp + 8) = o1;
    }
    __syncthreads();

    // ---- post MFMA, 4 waves: wave&1 = row group (16 rows), wave>>1 = head ----
    f32x4 zero = {0.f, 0.f, 0.f, 0.f};
    const int quad = lane >> 4, c16 = lane & 15;
    const int wq = wave & 1, hi = wave >> 1;
    const int rl = wq * 16 + c16;
    const bf16x8* wd = (const bf16x8*)(wbd_all + (size_t)m * 512 * 8);
    f32x4 pacc[2];
    pacc[0] = zero; pacc[1] = zero;
#pragma unroll
    for (int ks = 0; ks < 2; ks++) {
        bf16x8 a;
        int k0 = ks * 32 + quad * 8;
        u16x8 gv = *(const u16x8*)&ggl[rl * GLS + hi * 64 + k0];   // one ds_read_b128
#pragma unroll
        for (int j = 0; j < 8; j++)
            a[j] = (short)f2b(lrelu(b2f(gv[j]) + bconv[hi * 64 + k0 + j]));
#pragma unroll
        for (int nt2 = 0; nt2 < 2; nt2++) {
            int nt = hi * 2 + nt2;
            pacc[nt2] = __builtin_amdgcn_mfma_f32_16x16x32_bf16(a, wd[(nt * 2 + ks) * 64 + lane], pacc[nt2], 0, 0, 0);
        }
    }
    __syncthreads();   // all ggl reads done; zl may overwrite
    {
        const int rbl = wq * 16 + quad * 4;
#pragma unroll
        for (int nt2 = 0; nt2 < 2; nt2++) {
            int nt = hi * 2 + nt2;
            int col = nt * 16 + c16, hh = col >> 5, o = col & 31;
            float bias = bdec[hh * 32 + o];
#pragma unroll
            for (int j = 0; j < 4; j++) {
                int rl2 = rbl + j;
                int rg = blockIdx.x * GBR + rl2;
                zl[rl2 * 68 + col] = (rg < NN) ? (pacc[nt2][j] + bias) : 0.f;
            }
        }
    }
    __syncthreads();

    // ---- z store (256 threads, 32 rows) + score MFMA (4 waves, 8 N-tiles) ----
    {
        int rl2 = tid >> 3, cq = tid & 7;
        int rg = blockIdx.x * GBR + rl2;
        if (rg < NN) {
#pragma unroll
            for (int i = 0; i < 2; i++) {
                int c4 = (cq * 2 + i) * 4;
                float4 zv = *(const float4*)&zl[rl2 * 68 + c4];
                ushort4 o;
                o.x = f2b(zv.x); o.y = f2b(zv.y); o.z = f2b(zv.z); o.w = f2b(zv.w);
                *(ushort4*)&z[(size_t)rg * 64 + c4] = o;
            }
        }
    }
    float s = 0.f;
    {
        const bf16x8* wsb = (const bf16x8*)wbs;
        f32x4 sa[4];
#pragma unroll
        for (int nt2 = 0; nt2 < 4; nt2++) sa[nt2] = zero;
#pragma unroll
        for (int ks = 0; ks < 2; ks++) {
            bf16x8 a;
            const float* zp = &zl[rl * 68 + ks * 32 + quad * 8];
            f32x4 z0 = *(const f32x4*)zp;                          // vector LDS reads
            f32x4 z1 = *(const f32x4*)(zp + 4);
            a[0] = (short)f2b(z0[0]); a[1] = (short)f2b(z0[1]);
            a[2] = (short)f2b(z0[2]); a[3] = (short)f2b(z0[3]);
            a[4] = (short)f2b(z1[0]); a[5] = (short)f2b(z1[1]);
            a[6] = (short)f2b(z1[2]); a[7] = (short)f2b(z1[3]);
#pragma unroll
            for (int nt2 = 0; nt2 < 4; nt2++) {
                int nt = hi * 4 + nt2;
                sa[nt2] = __builtin_amdgcn_mfma_f32_16x16x32_bf16(a, wsb[(nt * 2 + ks) * 64 + lane], sa[nt2], 0, 0, 0);
            }
        }
        const int rbl = wq * 16 + quad * 4;
#pragma unroll
        for (int nt2 = 0; nt2 < 4; nt2++) {
            int nt = hi * 4 + nt2;
            int col = nt * 16 + c16;
            float qc = qv[col], bb = bs[col];
#pragma unroll
            for (int j = 0; j < 4; j++) {
                int rg = blockIdx.x * GBR + rbl + j;
                if (rg < NN) s += fast_tanh(sa[nt2][j] + bb) * qc;
            }
        }
#pragma unroll
        for (int off = 1; off < 64; off <<= 1) s += __shfl_xor(s, off);
    }
    if (lane == 0) spart[wave] = s;
    __syncthreads();
    if (tid == 0) {
        float t = spart[0] + spart[1] + spart[2] + spart[3];
        atomicAdd(&score[m], t);
    }
}

// ================= beta =================
__global__ void k_beta(const float* __restrict__ score, float* __restrict__ beta_ws,
                       float* __restrict__ out) {
    if (threadIdx.x == 0) {
        float s0 = score[0] / (float)NN, s1 = score[1] / (float)NN, s2 = score[2] / (float)NN;
        float mx = fmaxf(s0, fmaxf(s1, s2));
        float e0 = expf(s0 - mx), e1 = expf(s1 - mx), e2 = expf(s2 - mx);
        float inv = 1.f / (e0 + e1 + e2);
        beta_ws[0] = e0 * inv; beta_ws[1] = e1 * inv; beta_ws[2] = e2 * inv;
        out[800000] = e0 * inv; out[800001] = e1 * inv; out[800002] = e2 * inv;
    }
}

// ================= output: log_softmax((beta . z) @ W_o + b_o), z in bf16 =================
__global__ __launch_bounds__(256) void k_out(const u16* __restrict__ z,
                                             const float* __restrict__ beta,
                                             const float* __restrict__ Wo,
                                             const float* __restrict__ bo,
                                             float* __restrict__ out) {
    __shared__ float Zt[64 * 68];
    __shared__ float Wl[64 * 16];
    __shared__ float bl[16];
    const int tid = threadIdx.x, nbase = blockIdx.x * 64;
    float b0 = beta[0], b1 = beta[1], b2 = beta[2];
    for (int qq = tid; qq < 64 * 16; qq += 256) {
        int node = qq >> 4, k4 = qq & 15;
        int ng = nbase + node;
        float4 v = make_float4(0.f, 0.f, 0.f, 0.f);
        if (ng < NN) {
            ushort4 z0 = *(const ushort4*)&z[((size_t)0 * NN + ng) * 64 + k4 * 4];
            ushort4 z1 = *(const ushort4*)&z[((size_t)1 * NN + ng) * 64 + k4 * 4];
            ushort4 z2 = *(const ushort4*)&z[((size_t)2 * NN + ng) * 64 + k4 * 4];
            v.x = b0 * b2f(z0.x) + b1 * b2f(z1.x) + b2 * b2f(z2.x);
            v.y = b0 * b2f(z0.y) + b1 * b2f(z1.y) + b2 * b2f(z2.y);
            v.z = b0 * b2f(z0.z) + b1 * b2f(z1.z) + b2 * b2f(z2.z);
            v.w = b0 * b2f(z0.w) + b1 * b2f(z1.w) + b2 * b2f(z2.w);
        }
        *(float4*)&Zt[node * 68 + k4 * 4] = v;
    }
    for (int qq = tid; qq < 64 * 16 / 4; qq += 256)
        ((float4*)Wl)[qq] = ((const float4*)Wo)[qq];
    if (tid < 16) bl[tid] = bo[tid];
    __syncthreads();

    const int node = tid >> 2, cg = tid & 3;
    float4 a = make_float4(bl[cg * 4 + 0], bl[cg * 4 + 1], bl[cg * 4 + 2], bl[cg * 4 + 3]);
    for (int k = 0; k < 64; k++) {
        float zv = Zt[node * 68 + k];
        float4 w = *(const float4*)&Wl[k * 16 + cg * 4];
        a.x = fmaf(zv, w.x, a.x);
        a.y = fmaf(zv, w.y, a.y);
        a.z = fmaf(zv, w.z, a.z);
        a.w = fmaf(zv, w.w, a.w);
    }
    float mx = fmaxf(fmaxf(a.x, a.y), fmaxf(a.z, a.w));
    mx = fmaxf(mx, __shfl_xor(mx, 1));
    mx = fmaxf(mx, __shfl_xor(mx, 2));
    float sm = expf(a.x - mx) + expf(a.y - mx) + expf(a.z - mx) + expf(a.w - mx);
    sm += __shfl_xor(sm, 1);
    sm += __shfl_xor(sm, 2);
    float lse = mx + logf(sm);
    int ng = nbase + node;
    if (ng < NN) {
        float4 r = make_float4(a.x - lse, a.y - lse, a.z - lse, a.w - lse);
        *(float4*)&out[(size_t)ng * 16 + cg * 4] = r;
    }
}

extern "C" void kernel_launch(void* const* d_in, const int* in_sizes, int n_in,
                              void* d_out, int out_size, void* d_ws, size_t ws_size,
                              hipStream_t stream) {
    const float* x      = (const float*)d_in[0];
    const int*   ei     = (const int*)d_in[1];
    const float* W_enc  = (const float*)d_in[2];
    const float* b_enc  = (const float*)d_in[3];
    const float* W_conv = (const float*)d_in[4];
    const float* b_conv = (const float*)d_in[5];
    const float* W_dec  = (const float*)d_in[6];
    const float* b_dec  = (const float*)d_in[7];
    const float* W_s    = (const float*)d_in[8];
    const float* b_s    = (const float*)d_in[9];
    const float* qv     = (const float*)d_in[10];
    const float* W_o    = (const float*)d_in[11];
    const float* b_o    = (const float*)d_in[12];
    float* out = (float*)d_out;

    char* ws = (char*)d_ws;
    size_t off = 0;
    auto alloc = [&](size_t bytes) -> char* {
        char* p = ws + off;
        off = (off + bytes + 255) & ~(size_t)255;
        return p;
    };
    int*   row_ofs = (int*)alloc((size_t)MM * (NN + 1) * 4);
    float* rs      = (float*)alloc((size_t)MM * NN * 4);
    int*   sorted  = (int*)alloc((size_t)MM * EE * 4);
    u64*   queues  = (u64*)alloc((size_t)MM * NBKT * QCAP * 8);
    int*   gcur    = (int*)alloc((size_t)MM * NBKT * 4);
    int*   pbase   = (int*)alloc((size_t)MM * NBKT * 4);
    float* score   = (float*)alloc(64);
    float* beta_ws = (float*)alloc(64);
    u16*   wbe     = (u16*)alloc((size_t)MM * 2048 * 8 * 2);
    u16*   wbc     = (u16*)alloc((size_t)MM * 1024 * 8 * 2);
    u16*   wbd     = (u16*)alloc((size_t)MM * 512 * 8 * 2);
    u16*   wbs     = (u16*)alloc((size_t)1024 * 8 * 2);
    u8*    xw_buf  = (u8*)alloc((size_t)MM * XWN * 128);
    u16*   z_buf   = (u16*)alloc((size_t)MM * NN * 64 * 2);
    u16*   xb      = (u16*)alloc((size_t)NN * IND * 2);

    hipMemsetAsync(gcur, 0, (size_t)MM * NBKT * 4, stream);
    hipMemsetAsync(score, 0, 16, stream);

    dim3 gbkt(BBLK, MM);
    dim3 gcsr(NBKT, MM);
    k_bucket<<<gbkt, 256, 0, stream>>>(ei, queues, gcur);
    k_pscan<<<1, 64, 0, stream>>>(gcur, pbase);
    k_csr<<<gcsr, 512, 0, stream>>>(queues, gcur, pbase, row_ofs, rs, sorted);
    k_xcvt<<<(NN * IND / 8 + 255) / 256, 256, 0, stream>>>(x, xb);
    k_prep<<<46, 256, 0, stream>>>(W_enc, W_conv, W_dec, W_s, wbe, wbc, wbd, wbs);

    const int GB = (NN + 63) / 64;       // 782  (k_encconv, k_out)
    const int GB2 = (NN + GBR - 1) / GBR; // 1563 (k_gpost)
    dim3 gmm(GB, MM);
    dim3 gmg(GB2, MM);
    k_encconv<<<gmm, 256, 0, stream>>>(xb, wbe, b_enc, wbc, rs, xw_buf);
    k_gpost<<<gmg, 256, 0, stream>>>(sorted, row_ofs, rs, xw_buf,
                                     b_conv, wbd, b_dec, wbs, b_s, qv,
                                     z_buf, score);
    k_beta<<<1, 64, 0, stream>>>(score, beta_ws, out);
    k_out<<<GB, 256, 0, stream>>>(z_buf, beta_ws, W_o, b_o, out);
}

// Round 11
// 241.068 us; speedup vs baseline: 1.1011x; 1.1011x over previous
//
#include <hip/hip_runtime.h>

#define NN 50000
#define EE 800000
#define MM 3
#define HH 2
#define IND 128
#define HIDD 64
#define HEADD 32
#define OUTD 16
#define ATTD 128

#define NBKT 64
#define BSZ 782

#define NG4 200000
#define BBLK 196
#define QCAP 13200

#define GLS 136            // ggl LDS row stride (u16); zl overlays as float stride 68
#define XWN 50048          // xw rows per metapath incl. zero pad rows [NN, XWN)
#define XCB 3125           // xcvt blocks in fused k_xprep

typedef unsigned char u8;
typedef unsigned short u16;
typedef unsigned long long u64;
typedef short bf16x8 __attribute__((ext_vector_type(8)));
typedef unsigned short u16x8 __attribute__((ext_vector_type(8)));
typedef u64 u64x2 __attribute__((ext_vector_type(2)));
typedef unsigned int u32x4 __attribute__((ext_vector_type(4)));
typedef float f32x2 __attribute__((ext_vector_type(2)));
typedef float f32x4 __attribute__((ext_vector_type(4)));

__device__ __forceinline__ float lrelu(float v) { return v > 0.f ? v : 0.1f * v; }

__device__ __forceinline__ float fast_tanh(float x) {
    float ax = fabsf(x);
    float e = __expf(-2.0f * ax);
    float t = (1.0f - e) * __builtin_amdgcn_rcpf(1.0f + e);
    return copysignf(t, x);
}

__device__ __forceinline__ u16 f2b(float f) {          // fp32 -> bf16 RNE
    union { float f; unsigned int u; } v; v.f = f;
    unsigned int r = v.u + 0x7fffu + ((v.u >> 16) & 1u);
    return (u16)(r >> 16);
}
__device__ __forceinline__ float b2f(u16 u) {
    union { unsigned int u; float f; } v; v.u = ((unsigned int)u) << 16; return v.f;
}

__device__ __forceinline__ u8 f2e4hw(float f) {
    int r = __builtin_amdgcn_cvt_pk_fp8_f32(f, f, 0, false);
    return (u8)(r & 0xff);
}

// decode 16 fp8 bytes into 8 f32x2 partial accumulators via hw cvt
__device__ __forceinline__ void acc16(f32x2* acc, u32x4 w) {
#pragma unroll
    for (int i = 0; i < 4; i++) {
        acc[2 * i]     += __builtin_amdgcn_cvt_pk_f32_fp8(w[i], false);
        acc[2 * i + 1] += __builtin_amdgcn_cvt_pk_f32_fp8(w[i], true);
    }
}

// ================= phase A: bucket edges into 64 fine dst-buckets =================
__global__ __launch_bounds__(256) void k_bucket(const int* __restrict__ ei,
                                                u64* __restrict__ queues,
                                                int* __restrict__ gcur) {
    __shared__ int cnt[NBKT];
    __shared__ int base[NBKT];
    const int m = blockIdx.y, tid = threadIdx.x;
    const int4* s4 = (const int4*)(ei + (size_t)m * 2 * EE);
    const int4* d4 = (const int4*)(ei + (size_t)m * 2 * EE + EE);
    const int q0 = blockIdx.x * 1024;
    if (tid < NBKT) cnt[tid] = 0;
    __syncthreads();
#pragma unroll
    for (int i = 0; i < 4; i++) {
        int q = q0 + i * 256 + tid;
        if (q < NG4) {
            int4 v = d4[q];
            atomicAdd(&cnt[v.x / BSZ], 1);
            atomicAdd(&cnt[v.y / BSZ], 1);
            atomicAdd(&cnt[v.z / BSZ], 1);
            atomicAdd(&cnt[v.w / BSZ], 1);
        }
    }
    __syncthreads();
    if (tid < NBKT) { base[tid] = atomicAdd(&gcur[m * NBKT + tid], cnt[tid]); cnt[tid] = 0; }
    __syncthreads();
#pragma unroll
    for (int i = 0; i < 4; i++) {
        int q = q0 + i * 256 + tid;
        if (q < NG4) {
            int4 dv = d4[q];
            int4 sv = s4[q];
            int ds[4] = {dv.x, dv.y, dv.z, dv.w};
            int ss[4] = {sv.x, sv.y, sv.z, sv.w};
#pragma unroll
            for (int e = 0; e < 4; e++) {
                int b = ds[e] / BSZ;
                int slot = base[b] + atomicAdd(&cnt[b], 1);
                if (slot < QCAP) {
                    u64 pk = ((u64)(unsigned)ds[e] << 32) | (unsigned)ss[e];
                    queues[((size_t)(m * NBKT + b)) * QCAP + slot] = pk;
                }
            }
        }
    }
}

// ================= CSR build: one block owns one (m, bucket); pscan inlined =================
__global__ __launch_bounds__(512) void k_csr(const u64* __restrict__ queues,
                                             const int* __restrict__ gcur,
                                             int* __restrict__ ofs,
                                             float* __restrict__ rs,
                                             int* __restrict__ sorted) {
    __shared__ int cnt[BSZ];
    __shared__ int wscan[8];
    __shared__ int bb;                      // this bucket's base (exclusive prefix of gcur)
    const int m = blockIdx.y;
    const int b = blockIdx.x;
    const int tid = threadIdx.x;
    const int lane = tid & 63, w = tid >> 6;
    int qlen = gcur[m * NBKT + b]; if (qlen > QCAP) qlen = QCAP;
    const u64* q = queues + ((size_t)(m * NBKT + b)) * QCAP;
    const u64x2* q2 = (const u64x2*)q;
    const int dlo = b * BSZ;
    const int nd = min(dlo + BSZ, NN) - dlo;
    const int n2 = qlen >> 1;
    for (int i = tid; i < BSZ; i += 512) cnt[i] = 0;
    if (tid < 64) {                        // wave 0: inline pscan over the 64 buckets
        int L = gcur[m * NBKT + tid]; if (L > QCAP) L = QCAP;
        int v = L;
        for (int off = 1; off < 64; off <<= 1) { int t = __shfl_up(v, off); if (lane >= off) v += t; }
        if (tid == b) bb = v - L;          // exclusive prefix
    }
    __syncthreads();
    for (int i = tid; i < n2; i += 512) {
        u64x2 e = q2[i];
        atomicAdd(&cnt[(int)(e.x >> 32) - dlo], 1);
        atomicAdd(&cnt[(int)(e.y >> 32) - dlo], 1);
    }
    if (tid == 0 && (qlen & 1))
        atomicAdd(&cnt[(int)(q[qlen - 1] >> 32) - dlo], 1);
    __syncthreads();
    const int c0 = tid * 2;
    int v0 = (c0 < BSZ) ? cnt[c0] : 0;
    int v1 = (c0 + 1 < BSZ) ? cnt[c0 + 1] : 0;
    int s = v0 + v1;
    int vv = s;
    for (int off = 1; off < 64; off <<= 1) { int t = __shfl_up(vv, off); if (lane >= off) vv += t; }
    if (lane == 63) wscan[w] = vv;
    __syncthreads();
    if (tid == 0) { int run = 0; for (int j = 0; j < 8; j++) { int t = wscan[j]; wscan[j] = run; run += t; } }
    __syncthreads();
    int excl = wscan[w] + vv - s;
    int g0 = bb + excl;
    int g1 = g0 + v0;
    if (c0 < nd) {
        ofs[(size_t)m * (NN + 1) + dlo + c0] = g0;
        rs[(size_t)m * NN + dlo + c0] = rsqrtf((float)(v0 + 1));
    }
    if (c0 + 1 < nd) {
        ofs[(size_t)m * (NN + 1) + dlo + c0 + 1] = g1;
        rs[(size_t)m * NN + dlo + c0 + 1] = rsqrtf((float)(v1 + 1));
    }
    if (b == NBKT - 1 && tid == 0)
        ofs[(size_t)m * (NN + 1) + NN] = EE;
    __syncthreads();
    if (c0 < BSZ) cnt[c0] = g0;
    if (c0 + 1 < BSZ) cnt[c0 + 1] = g1;
    __syncthreads();
    int* srt = sorted + (size_t)m * EE;
    for (int i = tid; i < n2; i += 512) {
        u64x2 e = q2[i];
        int p0 = atomicAdd(&cnt[(int)(e.x >> 32) - dlo], 1);
        srt[p0] = (int)(e.x & 0xffffffffu);
        int p1 = atomicAdd(&cnt[(int)(e.y >> 32) - dlo], 1);
        srt[p1] = (int)(e.y & 0xffffffffu);
    }
    if (tid == 0 && (qlen & 1)) {
        u64 e = q[qlen - 1];
        int p0 = atomicAdd(&cnt[(int)(e >> 32) - dlo], 1);
        srt[p0] = (int)(e & 0xffffffffu);
    }
}

// ================= fused x->bf16 convert + weight prep (grid union) =================
__global__ __launch_bounds__(256) void k_xprep(const float* __restrict__ x,
                                               const float* __restrict__ We, const float* __restrict__ Wc,
                                               const float* __restrict__ Wd, const float* __restrict__ Ws,
                                               u16* __restrict__ xb,
                                               u16* __restrict__ wbe, u16* __restrict__ wbc,
                                               u16* __restrict__ wbd, u16* __restrict__ wbs) {
    if (blockIdx.x < XCB) {               // ---- xcvt part ----
        int t = blockIdx.x * 256 + threadIdx.x;      // 8 floats per thread; 3125*256 == NN*IND/8
        const float4* xp = (const float4*)x + (size_t)t * 2;
        float4 a = xp[0], b = xp[1];
        u16x8 o;
        o[0] = f2b(a.x); o[1] = f2b(a.y); o[2] = f2b(a.z); o[3] = f2b(a.w);
        o[4] = f2b(b.x); o[5] = f2b(b.y); o[6] = f2b(b.z); o[7] = f2b(b.w);
        *(u16x8*)&xb[(size_t)t * 8] = o;
        return;
    }
    int t = (blockIdx.x - XCB) * 256 + threadIdx.x;  // ---- prep part ----
    if (t >= 11776) return;
    bf16x8 val;
    u16* dst;
    if (t < 6144) {                       // enc
        int m = t >> 11, r = t & 2047;
        int nt = r >> 8, ks = (r >> 6) & 3, lane = r & 63;
        int n = nt * 16 + (lane & 15), h = n >> 6, o = n & 63;
        int kb = ks * 32 + (lane >> 4) * 8;
        const float* w = We + ((size_t)(m * 2 + h) * 128) * 64;
#pragma unroll
        for (int j = 0; j < 8; j++) val[j] = (short)f2b(w[(size_t)(kb + j) * 64 + o]);
        dst = wbe + ((size_t)m * 2048 + r) * 8;
    } else if (t < 9216) {                // conv
        int u = t - 6144;
        int m = u >> 10, r = u & 1023;
        int nt = r >> 7, ks = (r >> 6) & 1, lane = r & 63;
        int h = nt >> 2, o = (nt & 3) * 16 + (lane & 15);
        int kb = ks * 32 + (lane >> 4) * 8;
        const float* w = Wc + ((size_t)(m * 2 + h) * 64) * 64;
#pragma unroll
        for (int j = 0; j < 8; j++) val[j] = (short)f2b(w[(size_t)(kb + j) * 64 + o]);
        dst = wbc + ((size_t)m * 1024 + r) * 8;
    } else if (t < 10752) {               // dec
        int u = t - 9216;
        int m = u >> 9, r = u & 511;
        int nt = r >> 7, ks = (r >> 6) & 1, lane = r & 63;
        int h = nt >> 1, o = (nt & 1) * 16 + (lane & 15);
        int kb = ks * 32 + (lane >> 4) * 8;
        const float* w = Wd + ((size_t)(m * 2 + h) * 64) * 32;
#pragma unroll
        for (int j = 0; j < 8; j++) val[j] = (short)f2b(w[(size_t)(kb + j) * 32 + o]);
        dst = wbd + ((size_t)m * 512 + r) * 8;
    } else {                              // W_s
        int r = t - 10752;
        int nt = r >> 7, ks = (r >> 6) & 1, lane = r & 63;
        int n = nt * 16 + (lane & 15);
        int kb = ks * 32 + (lane >> 4) * 8;
#pragma unroll
        for (int j = 0; j < 8; j++) val[j] = (short)f2b(Ws[(size_t)(kb + j) * 128 + n]);
        dst = wbs + (size_t)r * 8;
    }
    *(bf16x8*)dst = val;
}

// ================= fused enc+conv (per metapath): xw' = e4m3(64 * rs[row] * (h @ Wc)) =================
#define HLS 133
__global__ __launch_bounds__(256) void k_encconv(const u16* __restrict__ xb,
                                                 const u16* __restrict__ wbe_all,
                                                 const float* __restrict__ be_all,
                                                 const u16* __restrict__ wbc_all,
                                                 const float* __restrict__ rs_all,
                                                 u8* __restrict__ xw_all) {
    __shared__ float hl[64 * HLS];
    const int m = blockIdx.y;
    const int tid = threadIdx.x, lane = tid & 63, wave = tid >> 6;
    const int quad = lane >> 4, c16 = lane & 15;
    const int row = blockIdx.x * 64 + wave * 16 + c16;
    const bool ok = row < NN;
    const bf16x8* wbE = (const bf16x8*)(wbe_all + (size_t)m * 2048 * 8);
    const float* be = be_all + m * 2 * 64;
    const float* rs = rs_all + (size_t)m * NN;
    u8* xw = xw_all + (size_t)m * XWN * 128;
    f32x4 zero = {0.f, 0.f, 0.f, 0.f};
    f32x4 acc[8];
#pragma unroll
    for (int nt = 0; nt < 8; nt++) acc[nt] = zero;
#pragma unroll
    for (int ks = 0; ks < 4; ks++) {
        bf16x8 a = {0, 0, 0, 0, 0, 0, 0, 0};
        if (ok) a = *(const bf16x8*)&xb[(size_t)row * 128 + ks * 32 + quad * 8];
#pragma unroll
        for (int nt = 0; nt < 8; nt++)
            acc[nt] = __builtin_amdgcn_mfma_f32_16x16x32_bf16(a, wbE[(nt * 4 + ks) * 64 + lane], acc[nt], 0, 0, 0);
    }
    const int rbl = wave * 16 + quad * 4;
#pragma unroll
    for (int nt = 0; nt < 8; nt++) {
        int col = nt * 16 + c16, hh = col >> 6, o = col & 63;
        float bias = be[hh * 64 + o];
#pragma unroll
        for (int j = 0; j < 4; j++) {
            int rl = rbl + j;
            int rg = blockIdx.x * 64 + rl;
            hl[rl * HLS + col] = (rg < NN) ? lrelu(acc[nt][j] + bias) : 0.f;
        }
    }
    __syncthreads();
    const bf16x8* wbC = (const bf16x8*)(wbc_all + (size_t)m * 1024 * 8);
    f32x4 cacc[8];
#pragma unroll
    for (int nt = 0; nt < 8; nt++) cacc[nt] = zero;
    const int rl = wave * 16 + c16;
#pragma unroll
    for (int ks = 0; ks < 2; ks++) {
        bf16x8 a0, a1;
        const float* hp = &hl[rl * HLS + ks * 32 + quad * 8];
#pragma unroll
        for (int j = 0; j < 8; j++) { a0[j] = (short)f2b(hp[j]); a1[j] = (short)f2b(hp[64 + j]); }
#pragma unroll
        for (int nt = 0; nt < 8; nt++)
            cacc[nt] = __builtin_amdgcn_mfma_f32_16x16x32_bf16(nt < 4 ? a0 : a1, wbC[(nt * 2 + ks) * 64 + lane], cacc[nt], 0, 0, 0);
    }
    float rsv[4];
#pragma unroll
    for (int j = 0; j < 4; j++) {
        int r = blockIdx.x * 64 + rbl + j;
        rsv[j] = (r < NN) ? rs[r] * 64.f : 0.f;
    }
#pragma unroll
    for (int nt = 0; nt < 8; nt++) {
        int col = nt * 16 + c16;
#pragma unroll
        for (int j = 0; j < 4; j++) {
            unsigned r = (unsigned)(blockIdx.x * 64 + rbl + j);
            // rows [NN, XWN) get rsv=0 -> e4m3(0) = 0x00 : zero pad row for gather clamping
            xw[(r << 7) + col] = f2e4hw(cacc[nt][j] * rsv[j]);
        }
    }
}

// ================= fused gather + post + score (R2-proven 512thr/8wave structure) =================
// gather: 8-lane group per dst; 2-buffer pipeline (8 rows in flight), shfl idx
// broadcast, 32-bit xw addressing.
__global__ __launch_bounds__(512) void k_gpost(const int* __restrict__ sorted_all,
                                               const int* __restrict__ ofs_all,
                                               const float* __restrict__ rs_all,
                                               const u8* __restrict__ xw_all,
                                               const float* __restrict__ bconv_all,
                                               const u16* __restrict__ wbd_all,
                                               const float* __restrict__ bdec_all,
                                               const u16* __restrict__ wbs,
                                               const float* __restrict__ bs,
                                               const float* __restrict__ qv,
                                               u16* __restrict__ z_all,
                                               float* __restrict__ score) {
    __shared__ u16 shm[64 * GLS];           // ggl (u16) / zl (float, stride 68) overlay
    __shared__ float spart[8];
    u16* ggl = shm;
    float* zl = (float*)shm;
    const int m = blockIdx.y;
    const int tid = threadIdx.x, lane = tid & 63, wave = tid >> 6;
    const int* sorted = sorted_all + (size_t)m * EE;
    const int* ofs = ofs_all + (size_t)m * (NN + 1);
    const float* rs = rs_all + (size_t)m * NN;
    const u8* xw = xw_all + (size_t)m * XWN * 128;
    const float* bconv = bconv_all + m * 2 * 64;
    const float* bdec = bdec_all + m * 2 * 32;
    u16* z = z_all + (size_t)m * NN * 64;

    // ---- gather ----
    {
        const int g = lane >> 3, c = lane & 7;
        const int wbase = blockIdx.x * 64 + wave * 8;
        const int dst = wbase + g;
        const bool on = dst < NN;
        int ov = 0;
        { int ii = wbase + lane; if (lane < 9) ov = ofs[ii > NN ? NN : ii]; }
        const int beg = __shfl(ov, g);
        const int deg = __shfl(ov, g + 1) - beg;       // 0 for dst >= NN
        int degmax = max(deg, __shfl_xor(deg, 8));
        degmax = max(degmax, __shfl_xor(degmax, 16));
        degmax = max(degmax, __shfl_xor(degmax, 32));  // wave-uniform
        const unsigned coff = (unsigned)(c * 16);

        // idx load: lanes (c&3)=k hold index of row j+k (clamped to zero pad row NN)
        auto lidx = [&](int j) -> int {
            int t = j + (c & 3);
            return (t < deg) ? sorted[beg + t] : NN;
        };
        // row loads: broadcast idx within group, each lane loads its 16B slice (32-bit addr)
        auto lrow = [&](int iv, u32x4* wv) {
#pragma unroll
            for (int k = 0; k < 4; k++) {
                int s = __shfl(iv, (lane & 0x38) + k);
                wv[k] = *(const u32x4*)(xw + (((unsigned)s << 7) + coff));
            }
        };

        f32x2 acc[8];
#pragma unroll
        for (int i = 0; i < 8; i++) acc[i] = 0.f;

        int i0 = lidx(0);
        int i1 = lidx(4);
        // own row (self-loop): 8 consecutive rows per wave, fully coalesced
        {
            unsigned sd = (unsigned)(on ? dst : NN);
            u32x4 w = *(const u32x4*)(xw + ((sd << 7) + coff));
            acc16(acc, w);
        }
        u32x4 wA[4], wB[4];
        lrow(i0, wA);
        const int nch = ((degmax + 7) >> 3) * 2;       // even #chunks of 4 rows
        for (int ch = 0; ch < nch; ch += 2) {
            lrow(i1, wB);                              // issue next chunk's rows
            i0 = lidx(ch * 4 + 8);                     // idx 2 chunks ahead
#pragma unroll
            for (int k = 0; k < 4; k++) acc16(acc, wA[k]);
            lrow(i0, wA);
            i1 = lidx(ch * 4 + 12);
#pragma unroll
            for (int k = 0; k < 4; k++) acc16(acc, wB[k]);
        }

        float rsv = on ? rs[dst] * (1.f / 64.f) : 0.f;
        u16x8 o0, o1;
#pragma unroll
        for (int i = 0; i < 4; i++) {
            o0[2 * i]     = f2b(acc[i].x * rsv);
            o0[2 * i + 1] = f2b(acc[i].y * rsv);
            o1[2 * i]     = f2b(acc[i + 4].x * rsv);
            o1[2 * i + 1] = f2b(acc[i + 4].y * rsv);
        }
        u16* gp = &ggl[(wave * 8 + g) * GLS + coff];
        *(u16x8*)gp = o0;
        *(u16x8*)(gp + 8) = o1;
    }
    __syncthreads();

    // ---- post MFMA, all 8 waves: wave&3 = row group, wave>>2 = head ----
    f32x4 zero = {0.f, 0.f, 0.f, 0.f};
    const int quad = lane >> 4, c16 = lane & 15;
    const int wq = wave & 3, hi = wave >> 2;
    const int rl = wq * 16 + c16;
    const bf16x8* wd = (const bf16x8*)(wbd_all + (size_t)m * 512 * 8);
    f32x4 pacc[2];
    pacc[0] = zero; pacc[1] = zero;
#pragma unroll
    for (int ks = 0; ks < 2; ks++) {
        bf16x8 a;
        int k0 = ks * 32 + quad * 8;
        u16x8 gv = *(const u16x8*)&ggl[rl * GLS + hi * 64 + k0];   // one ds_read_b128
#pragma unroll
        for (int j = 0; j < 8; j++)
            a[j] = (short)f2b(lrelu(b2f(gv[j]) + bconv[hi * 64 + k0 + j]));
#pragma unroll
        for (int nt2 = 0; nt2 < 2; nt2++) {
            int nt = hi * 2 + nt2;
            pacc[nt2] = __builtin_amdgcn_mfma_f32_16x16x32_bf16(a, wd[(nt * 2 + ks) * 64 + lane], pacc[nt2], 0, 0, 0);
        }
    }
    __syncthreads();   // all ggl reads done; zl may overwrite
    {
        const int rbl = wq * 16 + quad * 4;
#pragma unroll
        for (int nt2 = 0; nt2 < 2; nt2++) {
            int nt = hi * 2 + nt2;
            int col = nt * 16 + c16, hh = col >> 5, o = col & 31;
            float bias = bdec[hh * 32 + o];
#pragma unroll
            for (int j = 0; j < 4; j++) {
                int rl2 = rbl + j;
                int rg = blockIdx.x * 64 + rl2;
                zl[rl2 * 68 + col] = (rg < NN) ? (pacc[nt2][j] + bias) : 0.f;
            }
        }
    }
    __syncthreads();

    // ---- z store (512 threads) + score MFMA (8 waves: wave>>2 picks nt half) ----
    {
        int rl2 = tid >> 3, cq = tid & 7;
        int rg = blockIdx.x * 64 + rl2;
        if (rg < NN) {
#pragma unroll
            for (int i = 0; i < 2; i++) {
                int c4 = (cq * 2 + i) * 4;
                float4 zv = *(const float4*)&zl[rl2 * 68 + c4];
                ushort4 o;
                o.x = f2b(zv.x); o.y = f2b(zv.y); o.z = f2b(zv.z); o.w = f2b(zv.w);
                *(ushort4*)&z[(size_t)rg * 64 + c4] = o;
            }
        }
    }
    float s = 0.f;
    {
        const bf16x8* wsb = (const bf16x8*)wbs;
        f32x4 sa[4];
#pragma unroll
        for (int nt2 = 0; nt2 < 4; nt2++) sa[nt2] = zero;
#pragma unroll
        for (int ks = 0; ks < 2; ks++) {
            bf16x8 a;
            const float* zp = &zl[rl * 68 + ks * 32 + quad * 8];
            f32x4 z0 = *(const f32x4*)zp;                          // vector LDS reads
            f32x4 z1 = *(const f32x4*)(zp + 4);
            a[0] = (short)f2b(z0[0]); a[1] = (short)f2b(z0[1]);
            a[2] = (short)f2b(z0[2]); a[3] = (short)f2b(z0[3]);
            a[4] = (short)f2b(z1[0]); a[5] = (short)f2b(z1[1]);
            a[6] = (short)f2b(z1[2]); a[7] = (short)f2b(z1[3]);
#pragma unroll
            for (int nt2 = 0; nt2 < 4; nt2++) {
                int nt = hi * 4 + nt2;
                sa[nt2] = __builtin_amdgcn_mfma_f32_16x16x32_bf16(a, wsb[(nt * 2 + ks) * 64 + lane], sa[nt2], 0, 0, 0);
            }
        }
        const int rbl = wq * 16 + quad * 4;
#pragma unroll
        for (int nt2 = 0; nt2 < 4; nt2++) {
            int nt = hi * 4 + nt2;
            int col = nt * 16 + c16;
            float qc = qv[col], bb = bs[col];
#pragma unroll
            for (int j = 0; j < 4; j++) {
                int rg = blockIdx.x * 64 + rbl + j;
                if (rg < NN) s += fast_tanh(sa[nt2][j] + bb) * qc;
            }
        }
#pragma unroll
        for (int off = 1; off < 64; off <<= 1) s += __shfl_xor(s, off);
    }
    if (lane == 0) spart[wave] = s;
    __syncthreads();
    if (tid == 0) {
        float t = spart[0] + spart[1] + spart[2] + spart[3]
                + spart[4] + spart[5] + spart[6] + spart[7];
        atomicAdd(&score[m], t);
    }
}

// ================= output: log_softmax((beta . z) @ W_o + b_o); beta inlined =================
__global__ __launch_bounds__(256) void k_out(const u16* __restrict__ z,
                                             const float* __restrict__ score,
                                             const float* __restrict__ Wo,
                                             const float* __restrict__ bo,
                                             float* __restrict__ out) {
    __shared__ float Zt[64 * 68];
    __shared__ float Wl[64 * 16];
    __shared__ float bl[16];
    const int tid = threadIdx.x, nbase = blockIdx.x * 64;
    // beta from score (12B, L2-hot; recomputed per block)
    float s0 = score[0] * (1.f / NN), s1 = score[1] * (1.f / NN), s2 = score[2] * (1.f / NN);
    float mxb = fmaxf(s0, fmaxf(s1, s2));
    float e0 = __expf(s0 - mxb), e1 = __expf(s1 - mxb), e2 = __expf(s2 - mxb);
    float inv = 1.f / (e0 + e1 + e2);
    float b0 = e0 * inv, b1 = e1 * inv, b2 = e2 * inv;
    if (blockIdx.x == 0 && tid == 0) {
        out[800000] = b0; out[800001] = b1; out[800002] = b2;
    }
    for (int qq = tid; qq < 64 * 16; qq += 256) {
        int node = qq >> 4, k4 = qq & 15;
        int ng = nbase + node;
        float4 v = make_float4(0.f, 0.f, 0.f, 0.f);
        if (ng < NN) {
            ushort4 z0 = *(const ushort4*)&z[((size_t)0 * NN + ng) * 64 + k4 * 4];
            ushort4 z1 = *(const ushort4*)&z[((size_t)1 * NN + ng) * 64 + k4 * 4];
            ushort4 z2 = *(const ushort4*)&z[((size_t)2 * NN + ng) * 64 + k4 * 4];
            v.x = b0 * b2f(z0.x) + b1 * b2f(z1.x) + b2 * b2f(z2.x);
            v.y = b0 * b2f(z0.y) + b1 * b2f(z1.y) + b2 * b2f(z2.y);
            v.z = b0 * b2f(z0.z) + b1 * b2f(z1.z) + b2 * b2f(z2.z);
            v.w = b0 * b2f(z0.w) + b1 * b2f(z1.w) + b2 * b2f(z2.w);
        }
        *(float4*)&Zt[node * 68 + k4 * 4] = v;
    }
    for (int qq = tid; qq < 64 * 16 / 4; qq += 256)
        ((float4*)Wl)[qq] = ((const float4*)Wo)[qq];
    if (tid < 16) bl[tid] = bo[tid];
    __syncthreads();

    const int node = tid >> 2, cg = tid & 3;
    float4 a = make_float4(bl[cg * 4 + 0], bl[cg * 4 + 1], bl[cg * 4 + 2], bl[cg * 4 + 3]);
    for (int k = 0; k < 64; k++) {
        float zv = Zt[node * 68 + k];
        float4 w = *(const float4*)&Wl[k * 16 + cg * 4];
        a.x = fmaf(zv, w.x, a.x);
        a.y = fmaf(zv, w.y, a.y);
        a.z = fmaf(zv, w.z, a.z);
        a.w = fmaf(zv, w.w, a.w);
    }
    float mx = fmaxf(fmaxf(a.x, a.y), fmaxf(a.z, a.w));
    mx = fmaxf(mx, __shfl_xor(mx, 1));
    mx = fmaxf(mx, __shfl_xor(mx, 2));
    float sm = __expf(a.x - mx) + __expf(a.y - mx) + __expf(a.z - mx) + __expf(a.w - mx);
    sm += __shfl_xor(sm, 1);
    sm += __shfl_xor(sm, 2);
    float lse = mx + __logf(sm);
    int ng = nbase + node;
    if (ng < NN) {
        float4 r = make_float4(a.x - lse, a.y - lse, a.z - lse, a.w - lse);
        *(float4*)&out[(size_t)ng * 16 + cg * 4] = r;
    }
}

extern "C" void kernel_launch(void* const* d_in, const int* in_sizes, int n_in,
                              void* d_out, int out_size, void* d_ws, size_t ws_size,
                              hipStream_t stream) {
    const float* x      = (const float*)d_in[0];
    const int*   ei     = (const int*)d_in[1];
    const float* W_enc  = (const float*)d_in[2];
    const float* b_enc  = (const float*)d_in[3];
    const float* W_conv = (const float*)d_in[4];
    const float* b_conv = (const float*)d_in[5];
    const float* W_dec  = (const float*)d_in[6];
    const float* b_dec  = (const float*)d_in[7];
    const float* W_s    = (const float*)d_in[8];
    const float* b_s    = (const float*)d_in[9];
    const float* qv     = (const float*)d_in[10];
    const float* W_o    = (const float*)d_in[11];
    const float* b_o    = (const float*)d_in[12];
    float* out = (float*)d_out;

    char* ws = (char*)d_ws;
    size_t off = 0;
    auto alloc = [&](size_t bytes) -> char* {
        char* p = ws + off;
        off = (off + bytes + 255) & ~(size_t)255;
        return p;
    };
    int*   row_ofs = (int*)alloc((size_t)MM * (NN + 1) * 4);
    float* rs      = (float*)alloc((size_t)MM * NN * 4);
    int*   sorted  = (int*)alloc((size_t)MM * EE * 4);
    u64*   queues  = (u64*)alloc((size_t)MM * NBKT * QCAP * 8);
    int*   gcur    = (int*)alloc((size_t)MM * NBKT * 4);
    float* score   = (float*)alloc(64);
    u16*   wbe     = (u16*)alloc((size_t)MM * 2048 * 8 * 2);
    u16*   wbc     = (u16*)alloc((size_t)MM * 1024 * 8 * 2);
    u16*   wbd     = (u16*)alloc((size_t)MM * 512 * 8 * 2);
    u16*   wbs     = (u16*)alloc((size_t)1024 * 8 * 2);
    u8*    xw_buf  = (u8*)alloc((size_t)MM * XWN * 128);
    u16*   z_buf   = (u16*)alloc((size_t)MM * NN * 64 * 2);
    u16*   xb      = (u16*)alloc((size_t)NN * IND * 2);

    hipMemsetAsync(gcur, 0, (size_t)MM * NBKT * 4, stream);
    hipMemsetAsync(score, 0, 16, stream);

    dim3 gbkt(BBLK, MM);
    dim3 gcsr(NBKT, MM);
    k_bucket<<<gbkt, 256, 0, stream>>>(ei, queues, gcur);
    k_csr<<<gcsr, 512, 0, stream>>>(queues, gcur, row_ofs, rs, sorted);
    k_xprep<<<XCB + 46, 256, 0, stream>>>(x, W_enc, W_conv, W_dec, W_s,
                                          xb, wbe, wbc, wbd, wbs);

    const int GB = (NN + 63) / 64;   // 782
    dim3 gmm(GB, MM);
    k_encconv<<<gmm, 256, 0, stream>>>(xb, wbe, b_enc, wbc, rs, xw_buf);
    k_gpost<<<gmm, 512, 0, stream>>>(sorted, row_ofs, rs, xw_buf,
                                     b_conv, wbd, b_dec, wbs, b_s, qv,
                                     z_buf, score);
    k_out<<<GB, 256, 0, stream>>>(z_buf, score, W_o, b_o, out);
}

// Round 12
// 239.289 us; speedup vs baseline: 1.1093x; 1.0074x over previous
//
#include <hip/hip_runtime.h>

#define NN 50000
#define EE 800000
#define MM 3
#define HH 2
#define IND 128
#define HIDD 64
#define HEADD 32
#define OUTD 16
#define ATTD 128

#define NBKT 64
#define BSZ 782

#define NG4 200000
#define BBLK 196
#define QCAP 13200

#define GLS 136            // ggl LDS row stride (u16); zl overlays as float stride 68
#define XWN 50048          // xw rows per metapath incl. zero pad rows [NN, XWN)
#define XCB 3125           // xcvt blocks in fused k_xprep

typedef unsigned char u8;
typedef unsigned short u16;
typedef unsigned long long u64;
typedef short bf16x8 __attribute__((ext_vector_type(8)));
typedef unsigned short u16x8 __attribute__((ext_vector_type(8)));
typedef u64 u64x2 __attribute__((ext_vector_type(2)));
typedef unsigned int u32x4 __attribute__((ext_vector_type(4)));
typedef float f32x2 __attribute__((ext_vector_type(2)));
typedef float f32x4 __attribute__((ext_vector_type(4)));

__device__ __forceinline__ float lrelu(float v) { return v > 0.f ? v : 0.1f * v; }

__device__ __forceinline__ float fast_tanh(float x) {
    float ax = fabsf(x);
    float e = __expf(-2.0f * ax);
    float t = (1.0f - e) * __builtin_amdgcn_rcpf(1.0f + e);
    return copysignf(t, x);
}

__device__ __forceinline__ u16 f2b(float f) {          // fp32 -> bf16 RNE
    union { float f; unsigned int u; } v; v.f = f;
    unsigned int r = v.u + 0x7fffu + ((v.u >> 16) & 1u);
    return (u16)(r >> 16);
}
__device__ __forceinline__ float b2f(u16 u) {
    union { unsigned int u; float f; } v; v.u = ((unsigned int)u) << 16; return v.f;
}

__device__ __forceinline__ u8 f2e4hw(float f) {
    int r = __builtin_amdgcn_cvt_pk_fp8_f32(f, f, 0, false);
    return (u8)(r & 0xff);
}

// decode 16 fp8 bytes into 8 f32x2 partial accumulators via hw cvt
__device__ __forceinline__ void acc16(f32x2* acc, u32x4 w) {
#pragma unroll
    for (int i = 0; i < 4; i++) {
        acc[2 * i]     += __builtin_amdgcn_cvt_pk_f32_fp8(w[i], false);
        acc[2 * i + 1] += __builtin_amdgcn_cvt_pk_f32_fp8(w[i], true);
    }
}

// ================= fused x->bf16 convert + weight prep + buffer zeroing =================
// Launched FIRST: block 0 also zeroes gcur (192 ints) and score (4 floats),
// replacing two hipMemsetAsync graph nodes.
__global__ __launch_bounds__(256) void k_xprep(const float* __restrict__ x,
                                               const float* __restrict__ We, const float* __restrict__ Wc,
                                               const float* __restrict__ Wd, const float* __restrict__ Ws,
                                               u16* __restrict__ xb,
                                               u16* __restrict__ wbe, u16* __restrict__ wbc,
                                               u16* __restrict__ wbd, u16* __restrict__ wbs,
                                               int* __restrict__ gcur, float* __restrict__ score) {
    if (blockIdx.x == 0) {
        if (threadIdx.x < MM * NBKT) gcur[threadIdx.x] = 0;
        if (threadIdx.x < 4) score[threadIdx.x] = 0.f;
    }
    if (blockIdx.x < XCB) {               // ---- xcvt part ----
        int t = blockIdx.x * 256 + threadIdx.x;      // 8 floats per thread; 3125*256 == NN*IND/8
        const float4* xp = (const float4*)x + (size_t)t * 2;
        float4 a = xp[0], b = xp[1];
        u16x8 o;
        o[0] = f2b(a.x); o[1] = f2b(a.y); o[2] = f2b(a.z); o[3] = f2b(a.w);
        o[4] = f2b(b.x); o[5] = f2b(b.y); o[6] = f2b(b.z); o[7] = f2b(b.w);
        *(u16x8*)&xb[(size_t)t * 8] = o;
        return;
    }
    int t = (blockIdx.x - XCB) * 256 + threadIdx.x;  // ---- prep part ----
    if (t >= 11776) return;
    bf16x8 val;
    u16* dst;
    if (t < 6144) {                       // enc
        int m = t >> 11, r = t & 2047;
        int nt = r >> 8, ks = (r >> 6) & 3, lane = r & 63;
        int n = nt * 16 + (lane & 15), h = n >> 6, o = n & 63;
        int kb = ks * 32 + (lane >> 4) * 8;
        const float* w = We + ((size_t)(m * 2 + h) * 128) * 64;
#pragma unroll
        for (int j = 0; j < 8; j++) val[j] = (short)f2b(w[(size_t)(kb + j) * 64 + o]);
        dst = wbe + ((size_t)m * 2048 + r) * 8;
    } else if (t < 9216) {                // conv
        int u = t - 6144;
        int m = u >> 10, r = u & 1023;
        int nt = r >> 7, ks = (r >> 6) & 1, lane = r & 63;
        int h = nt >> 2, o = (nt & 3) * 16 + (lane & 15);
        int kb = ks * 32 + (lane >> 4) * 8;
        const float* w = Wc + ((size_t)(m * 2 + h) * 64) * 64;
#pragma unroll
        for (int j = 0; j < 8; j++) val[j] = (short)f2b(w[(size_t)(kb + j) * 64 + o]);
        dst = wbc + ((size_t)m * 1024 + r) * 8;
    } else if (t < 10752) {               // dec
        int u = t - 9216;
        int m = u >> 9, r = u & 511;
        int nt = r >> 7, ks = (r >> 6) & 1, lane = r & 63;
        int h = nt >> 1, o = (nt & 1) * 16 + (lane & 15);
        int kb = ks * 32 + (lane >> 4) * 8;
        const float* w = Wd + ((size_t)(m * 2 + h) * 64) * 32;
#pragma unroll
        for (int j = 0; j < 8; j++) val[j] = (short)f2b(w[(size_t)(kb + j) * 32 + o]);
        dst = wbd + ((size_t)m * 512 + r) * 8;
    } else {                              // W_s
        int r = t - 10752;
        int nt = r >> 7, ks = (r >> 6) & 1, lane = r & 63;
        int n = nt * 16 + (lane & 15);
        int kb = ks * 32 + (lane >> 4) * 8;
#pragma unroll
        for (int j = 0; j < 8; j++) val[j] = (short)f2b(Ws[(size_t)(kb + j) * 128 + n]);
        dst = wbs + (size_t)r * 8;
    }
    *(bf16x8*)dst = val;
}

// ================= phase A: bucket edges into 64 fine dst-buckets =================
__global__ __launch_bounds__(256) void k_bucket(const int* __restrict__ ei,
                                                u64* __restrict__ queues,
                                                int* __restrict__ gcur) {
    __shared__ int cnt[NBKT];
    __shared__ int base[NBKT];
    const int m = blockIdx.y, tid = threadIdx.x;
    const int4* s4 = (const int4*)(ei + (size_t)m * 2 * EE);
    const int4* d4 = (const int4*)(ei + (size_t)m * 2 * EE + EE);
    const int q0 = blockIdx.x * 1024;
    if (tid < NBKT) cnt[tid] = 0;
    __syncthreads();
#pragma unroll
    for (int i = 0; i < 4; i++) {
        int q = q0 + i * 256 + tid;
        if (q < NG4) {
            int4 v = d4[q];
            atomicAdd(&cnt[v.x / BSZ], 1);
            atomicAdd(&cnt[v.y / BSZ], 1);
            atomicAdd(&cnt[v.z / BSZ], 1);
            atomicAdd(&cnt[v.w / BSZ], 1);
        }
    }
    __syncthreads();
    if (tid < NBKT) { base[tid] = atomicAdd(&gcur[m * NBKT + tid], cnt[tid]); cnt[tid] = 0; }
    __syncthreads();
#pragma unroll
    for (int i = 0; i < 4; i++) {
        int q = q0 + i * 256 + tid;
        if (q < NG4) {
            int4 dv = d4[q];
            int4 sv = s4[q];
            int ds[4] = {dv.x, dv.y, dv.z, dv.w};
            int ss[4] = {sv.x, sv.y, sv.z, sv.w};
#pragma unroll
            for (int e = 0; e < 4; e++) {
                int b = ds[e] / BSZ;
                int slot = base[b] + atomicAdd(&cnt[b], 1);
                if (slot < QCAP) {
                    u64 pk = ((u64)(unsigned)ds[e] << 32) | (unsigned)ss[e];
                    queues[((size_t)(m * NBKT + b)) * QCAP + slot] = pk;
                }
            }
        }
    }
}

// ================= CSR build: one block owns one (m, bucket); pscan inlined =================
__global__ __launch_bounds__(512) void k_csr(const u64* __restrict__ queues,
                                             const int* __restrict__ gcur,
                                             int* __restrict__ ofs,
                                             float* __restrict__ rs,
                                             int* __restrict__ sorted) {
    __shared__ int cnt[BSZ];
    __shared__ int wscan[8];
    __shared__ int bb;                      // this bucket's base (exclusive prefix of gcur)
    const int m = blockIdx.y;
    const int b = blockIdx.x;
    const int tid = threadIdx.x;
    const int lane = tid & 63, w = tid >> 6;
    int qlen = gcur[m * NBKT + b]; if (qlen > QCAP) qlen = QCAP;
    const u64* q = queues + ((size_t)(m * NBKT + b)) * QCAP;
    const u64x2* q2 = (const u64x2*)q;
    const int dlo = b * BSZ;
    const int nd = min(dlo + BSZ, NN) - dlo;
    const int n2 = qlen >> 1;
    for (int i = tid; i < BSZ; i += 512) cnt[i] = 0;
    if (tid < 64) {                        // wave 0: inline pscan over the 64 buckets
        int L = gcur[m * NBKT + tid]; if (L > QCAP) L = QCAP;
        int v = L;
        for (int off = 1; off < 64; off <<= 1) { int t = __shfl_up(v, off); if (lane >= off) v += t; }
        if (tid == b) bb = v - L;          // exclusive prefix
    }
    __syncthreads();
    for (int i = tid; i < n2; i += 512) {
        u64x2 e = q2[i];
        atomicAdd(&cnt[(int)(e.x >> 32) - dlo], 1);
        atomicAdd(&cnt[(int)(e.y >> 32) - dlo], 1);
    }
    if (tid == 0 && (qlen & 1))
        atomicAdd(&cnt[(int)(q[qlen - 1] >> 32) - dlo], 1);
    __syncthreads();
    const int c0 = tid * 2;
    int v0 = (c0 < BSZ) ? cnt[c0] : 0;
    int v1 = (c0 + 1 < BSZ) ? cnt[c0 + 1] : 0;
    int s = v0 + v1;
    int vv = s;
    for (int off = 1; off < 64; off <<= 1) { int t = __shfl_up(vv, off); if (lane >= off) vv += t; }
    if (lane == 63) wscan[w] = vv;
    __syncthreads();
    if (tid == 0) { int run = 0; for (int j = 0; j < 8; j++) { int t = wscan[j]; wscan[j] = run; run += t; } }
    __syncthreads();
    int excl = wscan[w] + vv - s;
    int g0 = bb + excl;
    int g1 = g0 + v0;
    if (c0 < nd) {
        ofs[(size_t)m * (NN + 1) + dlo + c0] = g0;
        rs[(size_t)m * NN + dlo + c0] = rsqrtf((float)(v0 + 1));
    }
    if (c0 + 1 < nd) {
        ofs[(size_t)m * (NN + 1) + dlo + c0 + 1] = g1;
        rs[(size_t)m * NN + dlo + c0 + 1] = rsqrtf((float)(v1 + 1));
    }
    if (b == NBKT - 1 && tid == 0)
        ofs[(size_t)m * (NN + 1) + NN] = EE;
    __syncthreads();
    if (c0 < BSZ) cnt[c0] = g0;
    if (c0 + 1 < BSZ) cnt[c0 + 1] = g1;
    __syncthreads();
    int* srt = sorted + (size_t)m * EE;
    for (int i = tid; i < n2; i += 512) {
        u64x2 e = q2[i];
        int p0 = atomicAdd(&cnt[(int)(e.x >> 32) - dlo], 1);
        srt[p0] = (int)(e.x & 0xffffffffu);
        int p1 = atomicAdd(&cnt[(int)(e.y >> 32) - dlo], 1);
        srt[p1] = (int)(e.y & 0xffffffffu);
    }
    if (tid == 0 && (qlen & 1)) {
        u64 e = q[qlen - 1];
        int p0 = atomicAdd(&cnt[(int)(e >> 32) - dlo], 1);
        srt[p0] = (int)(e & 0xffffffffu);
    }
}

// ================= fused enc+conv (per metapath): xw' = e4m3(64 * rs[row] * (h @ Wc)) =================
#define HLS 133
__global__ __launch_bounds__(256) void k_encconv(const u16* __restrict__ xb,
                                                 const u16* __restrict__ wbe_all,
                                                 const float* __restrict__ be_all,
                                                 const u16* __restrict__ wbc_all,
                                                 const float* __restrict__ rs_all,
                                                 u8* __restrict__ xw_all) {
    __shared__ float hl[64 * HLS];
    const int m = blockIdx.y;
    const int tid = threadIdx.x, lane = tid & 63, wave = tid >> 6;
    const int quad = lane >> 4, c16 = lane & 15;
    const int row = blockIdx.x * 64 + wave * 16 + c16;
    const bool ok = row < NN;
    const bf16x8* wbE = (const bf16x8*)(wbe_all + (size_t)m * 2048 * 8);
    const float* be = be_all + m * 2 * 64;
    const float* rs = rs_all + (size_t)m * NN;
    u8* xw = xw_all + (size_t)m * XWN * 128;
    f32x4 zero = {0.f, 0.f, 0.f, 0.f};
    f32x4 acc[8];
#pragma unroll
    for (int nt = 0; nt < 8; nt++) acc[nt] = zero;
#pragma unroll
    for (int ks = 0; ks < 4; ks++) {
        bf16x8 a = {0, 0, 0, 0, 0, 0, 0, 0};
        if (ok) a = *(const bf16x8*)&xb[(size_t)row * 128 + ks * 32 + quad * 8];
#pragma unroll
        for (int nt = 0; nt < 8; nt++)
            acc[nt] = __builtin_amdgcn_mfma_f32_16x16x32_bf16(a, wbE[(nt * 4 + ks) * 64 + lane], acc[nt], 0, 0, 0);
    }
    const int rbl = wave * 16 + quad * 4;
#pragma unroll
    for (int nt = 0; nt < 8; nt++) {
        int col = nt * 16 + c16, hh = col >> 6, o = col & 63;
        float bias = be[hh * 64 + o];
#pragma unroll
        for (int j = 0; j < 4; j++) {
            int rl = rbl + j;
            int rg = blockIdx.x * 64 + rl;
            hl[rl * HLS + col] = (rg < NN) ? lrelu(acc[nt][j] + bias) : 0.f;
        }
    }
    __syncthreads();
    const bf16x8* wbC = (const bf16x8*)(wbc_all + (size_t)m * 1024 * 8);
    f32x4 cacc[8];
#pragma unroll
    for (int nt = 0; nt < 8; nt++) cacc[nt] = zero;
    const int rl = wave * 16 + c16;
#pragma unroll
    for (int ks = 0; ks < 2; ks++) {
        bf16x8 a0, a1;
        const float* hp = &hl[rl * HLS + ks * 32 + quad * 8];
#pragma unroll
        for (int j = 0; j < 8; j++) { a0[j] = (short)f2b(hp[j]); a1[j] = (short)f2b(hp[64 + j]); }
#pragma unroll
        for (int nt = 0; nt < 8; nt++)
            cacc[nt] = __builtin_amdgcn_mfma_f32_16x16x32_bf16(nt < 4 ? a0 : a1, wbC[(nt * 2 + ks) * 64 + lane], cacc[nt], 0, 0, 0);
    }
    float rsv[4];
#pragma unroll
    for (int j = 0; j < 4; j++) {
        int r = blockIdx.x * 64 + rbl + j;
        rsv[j] = (r < NN) ? rs[r] * 64.f : 0.f;
    }
#pragma unroll
    for (int nt = 0; nt < 8; nt++) {
        int col = nt * 16 + c16;
#pragma unroll
        for (int j = 0; j < 4; j++) {
            int r = blockIdx.x * 64 + rbl + j;
            // rows [NN, XWN) get rsv=0 -> e4m3(0) = 0x00 : zero pad row for gather clamping
            xw[(size_t)r * 128 + col] = f2e4hw(cacc[nt][j] * rsv[j]);
        }
    }
}

// ================= fused gather + post + score (R2-proven 512thr/8wave structure) =================
// gather: 8-lane group per dst; 2-buffer pipeline (8 rows in flight), shfl idx
// broadcast, 64-bit xw addressing (32-bit form measured slower, R11).
__global__ __launch_bounds__(512) void k_gpost(const int* __restrict__ sorted_all,
                                               const int* __restrict__ ofs_all,
                                               const float* __restrict__ rs_all,
                                               const u8* __restrict__ xw_all,
                                               const float* __restrict__ bconv_all,
                                               const u16* __restrict__ wbd_all,
                                               const float* __restrict__ bdec_all,
                                               const u16* __restrict__ wbs,
                                               const float* __restrict__ bs,
                                               const float* __restrict__ qv,
                                               u16* __restrict__ z_all,
                                               float* __restrict__ score) {
    __shared__ u16 shm[64 * GLS];           // ggl (u16) / zl (float, stride 68) overlay
    __shared__ float spart[8];
    u16* ggl = shm;
    float* zl = (float*)shm;
    const int m = blockIdx.y;
    const int tid = threadIdx.x, lane = tid & 63, wave = tid >> 6;
    const int* sorted = sorted_all + (size_t)m * EE;
    const int* ofs = ofs_all + (size_t)m * (NN + 1);
    const float* rs = rs_all + (size_t)m * NN;
    const u8* xw = xw_all + (size_t)m * XWN * 128;
    const float* bconv = bconv_all + m * 2 * 64;
    const float* bdec = bdec_all + m * 2 * 32;
    u16* z = z_all + (size_t)m * NN * 64;

    // ---- gather ----
    {
        const int g = lane >> 3, c = lane & 7;
        const int wbase = blockIdx.x * 64 + wave * 8;
        const int dst = wbase + g;
        const bool on = dst < NN;
        int ov = 0;
        { int ii = wbase + lane; if (lane < 9) ov = ofs[ii > NN ? NN : ii]; }
        const int beg = __shfl(ov, g);
        const int deg = __shfl(ov, g + 1) - beg;       // 0 for dst >= NN
        int degmax = max(deg, __shfl_xor(deg, 8));
        degmax = max(degmax, __shfl_xor(degmax, 16));
        degmax = max(degmax, __shfl_xor(degmax, 32));  // wave-uniform
        const int coff = c * 16;

        // idx load: lanes (c&3)=k hold index of row j+k (clamped to zero pad row NN)
        auto lidx = [&](int j) -> int {
            int t = j + (c & 3);
            return (t < deg) ? sorted[beg + t] : NN;
        };
        // row loads: broadcast idx within group, each lane loads its 16B slice
        auto lrow = [&](int iv, u32x4* wv) {
#pragma unroll
            for (int k = 0; k < 4; k++) {
                int s = __shfl(iv, (lane & 0x38) + k);
                wv[k] = *(const u32x4*)&xw[(size_t)s * 128 + coff];
            }
        };

        f32x2 acc[8];
#pragma unroll
        for (int i = 0; i < 8; i++) acc[i] = 0.f;

        int i0 = lidx(0);
        int i1 = lidx(4);
        // own row (self-loop): 8 consecutive rows per wave, fully coalesced
        {
            int sd = on ? dst : NN;
            u32x4 w = *(const u32x4*)&xw[(size_t)sd * 128 + coff];
            acc16(acc, w);
        }
        u32x4 wA[4], wB[4];
        lrow(i0, wA);
        const int nch = ((degmax + 7) >> 3) * 2;       // even #chunks of 4 rows
        for (int ch = 0; ch < nch; ch += 2) {
            lrow(i1, wB);                              // issue next chunk's rows
            i0 = lidx(ch * 4 + 8);                     // idx 2 chunks ahead
#pragma unroll
            for (int k = 0; k < 4; k++) acc16(acc, wA[k]);
            lrow(i0, wA);
            i1 = lidx(ch * 4 + 12);
#pragma unroll
            for (int k = 0; k < 4; k++) acc16(acc, wB[k]);
        }

        float rsv = on ? rs[dst] * (1.f / 64.f) : 0.f;
        u16x8 o0, o1;
#pragma unroll
        for (int i = 0; i < 4; i++) {
            o0[2 * i]     = f2b(acc[i].x * rsv);
            o0[2 * i + 1] = f2b(acc[i].y * rsv);
            o1[2 * i]     = f2b(acc[i + 4].x * rsv);
            o1[2 * i + 1] = f2b(acc[i + 4].y * rsv);
        }
        u16* gp = &ggl[(wave * 8 + g) * GLS + coff];
        *(u16x8*)gp = o0;
        *(u16x8*)(gp + 8) = o1;
    }
    __syncthreads();

    // ---- post MFMA, all 8 waves: wave&3 = row group, wave>>2 = head ----
    f32x4 zero = {0.f, 0.f, 0.f, 0.f};
    const int quad = lane >> 4, c16 = lane & 15;
    const int wq = wave & 3, hi = wave >> 2;
    const int rl = wq * 16 + c16;
    const bf16x8* wd = (const bf16x8*)(wbd_all + (size_t)m * 512 * 8);
    f32x4 pacc[2];
    pacc[0] = zero; pacc[1] = zero;
#pragma unroll
    for (int ks = 0; ks < 2; ks++) {
        bf16x8 a;
        int k0 = ks * 32 + quad * 8;
        u16x8 gv = *(const u16x8*)&ggl[rl * GLS + hi * 64 + k0];   // one ds_read_b128
#pragma unroll
        for (int j = 0; j < 8; j++)
            a[j] = (short)f2b(lrelu(b2f(gv[j]) + bconv[hi * 64 + k0 + j]));
#pragma unroll
        for (int nt2 = 0; nt2 < 2; nt2++) {
            int nt = hi * 2 + nt2;
            pacc[nt2] = __builtin_amdgcn_mfma_f32_16x16x32_bf16(a, wd[(nt * 2 + ks) * 64 + lane], pacc[nt2], 0, 0, 0);
        }
    }
    __syncthreads();   // all ggl reads done; zl may overwrite
    {
        const int rbl = wq * 16 + quad * 4;
#pragma unroll
        for (int nt2 = 0; nt2 < 2; nt2++) {
            int nt = hi * 2 + nt2;
            int col = nt * 16 + c16, hh = col >> 5, o = col & 31;
            float bias = bdec[hh * 32 + o];
#pragma unroll
            for (int j = 0; j < 4; j++) {
                int rl2 = rbl + j;
                int rg = blockIdx.x * 64 + rl2;
                zl[rl2 * 68 + col] = (rg < NN) ? (pacc[nt2][j] + bias) : 0.f;
            }
        }
    }
    __syncthreads();

    // ---- z store (512 threads) + score MFMA (8 waves: wave>>2 picks nt half) ----
    {
        int rl2 = tid >> 3, cq = tid & 7;
        int rg = blockIdx.x * 64 + rl2;
        if (rg < NN) {
#pragma unroll
            for (int i = 0; i < 2; i++) {
                int c4 = (cq * 2 + i) * 4;
                float4 zv = *(const float4*)&zl[rl2 * 68 + c4];
                ushort4 o;
                o.x = f2b(zv.x); o.y = f2b(zv.y); o.z = f2b(zv.z); o.w = f2b(zv.w);
                *(ushort4*)&z[(size_t)rg * 64 + c4] = o;
            }
        }
    }
    float s = 0.f;
    {
        const bf16x8* wsb = (const bf16x8*)wbs;
        f32x4 sa[4];
#pragma unroll
        for (int nt2 = 0; nt2 < 4; nt2++) sa[nt2] = zero;
#pragma unroll
        for (int ks = 0; ks < 2; ks++) {
            bf16x8 a;
            const float* zp = &zl[rl * 68 + ks * 32 + quad * 8];
            f32x4 z0 = *(const f32x4*)zp;                          // vector LDS reads
            f32x4 z1 = *(const f32x4*)(zp + 4);
            a[0] = (short)f2b(z0[0]); a[1] = (short)f2b(z0[1]);
            a[2] = (short)f2b(z0[2]); a[3] = (short)f2b(z0[3]);
            a[4] = (short)f2b(z1[0]); a[5] = (short)f2b(z1[1]);
            a[6] = (short)f2b(z1[2]); a[7] = (short)f2b(z1[3]);
#pragma unroll
            for (int nt2 = 0; nt2 < 4; nt2++) {
                int nt = hi * 4 + nt2;
                sa[nt2] = __builtin_amdgcn_mfma_f32_16x16x32_bf16(a, wsb[(nt * 2 + ks) * 64 + lane], sa[nt2], 0, 0, 0);
            }
        }
        const int rbl = wq * 16 + quad * 4;
#pragma unroll
        for (int nt2 = 0; nt2 < 4; nt2++) {
            int nt = hi * 4 + nt2;
            int col = nt * 16 + c16;
            float qc = qv[col], bb = bs[col];
#pragma unroll
            for (int j = 0; j < 4; j++) {
                int rg = blockIdx.x * 64 + rbl + j;
                if (rg < NN) s += fast_tanh(sa[nt2][j] + bb) * qc;
            }
        }
#pragma unroll
        for (int off = 1; off < 64; off <<= 1) s += __shfl_xor(s, off);
    }
    if (lane == 0) spart[wave] = s;
    __syncthreads();
    if (tid == 0) {
        float t = spart[0] + spart[1] + spart[2] + spart[3]
                + spart[4] + spart[5] + spart[6] + spart[7];
        atomicAdd(&score[m], t);
    }
}

// ================= output: log_softmax((beta . z) @ W_o + b_o); beta inlined =================
__global__ __launch_bounds__(256) void k_out(const u16* __restrict__ z,
                                             const float* __restrict__ score,
                                             const float* __restrict__ Wo,
                                             const float* __restrict__ bo,
                                             float* __restrict__ out) {
    __shared__ float Zt[64 * 68];
    __shared__ float Wl[64 * 16];
    __shared__ float bl[16];
    const int tid = threadIdx.x, nbase = blockIdx.x * 64;
    // beta from score (12B, L2-hot; recomputed per block)
    float s0 = score[0] * (1.f / NN), s1 = score[1] * (1.f / NN), s2 = score[2] * (1.f / NN);
    float mxb = fmaxf(s0, fmaxf(s1, s2));
    float e0 = __expf(s0 - mxb), e1 = __expf(s1 - mxb), e2 = __expf(s2 - mxb);
    float inv = 1.f / (e0 + e1 + e2);
    float b0 = e0 * inv, b1 = e1 * inv, b2 = e2 * inv;
    if (blockIdx.x == 0 && tid == 0) {
        out[800000] = b0; out[800001] = b1; out[800002] = b2;
    }
    for (int qq = tid; qq < 64 * 16; qq += 256) {
        int node = qq >> 4, k4 = qq & 15;
        int ng = nbase + node;
        float4 v = make_float4(0.f, 0.f, 0.f, 0.f);
        if (ng < NN) {
            ushort4 z0 = *(const ushort4*)&z[((size_t)0 * NN + ng) * 64 + k4 * 4];
            ushort4 z1 = *(const ushort4*)&z[((size_t)1 * NN + ng) * 64 + k4 * 4];
            ushort4 z2 = *(const ushort4*)&z[((size_t)2 * NN + ng) * 64 + k4 * 4];
            v.x = b0 * b2f(z0.x) + b1 * b2f(z1.x) + b2 * b2f(z2.x);
            v.y = b0 * b2f(z0.y) + b1 * b2f(z1.y) + b2 * b2f(z2.y);
            v.z = b0 * b2f(z0.z) + b1 * b2f(z1.z) + b2 * b2f(z2.z);
            v.w = b0 * b2f(z0.w) + b1 * b2f(z1.w) + b2 * b2f(z2.w);
        }
        *(float4*)&Zt[node * 68 + k4 * 4] = v;
    }
    for (int qq = tid; qq < 64 * 16 / 4; qq += 256)
        ((float4*)Wl)[qq] = ((const float4*)Wo)[qq];
    if (tid < 16) bl[tid] = bo[tid];
    __syncthreads();

    const int node = tid >> 2, cg = tid & 3;
    float4 a = make_float4(bl[cg * 4 + 0], bl[cg * 4 + 1], bl[cg * 4 + 2], bl[cg * 4 + 3]);
    for (int k = 0; k < 64; k++) {
        float zv = Zt[node * 68 + k];
        float4 w = *(const float4*)&Wl[k * 16 + cg * 4];
        a.x = fmaf(zv, w.x, a.x);
        a.y = fmaf(zv, w.y, a.y);
        a.z = fmaf(zv, w.z, a.z);
        a.w = fmaf(zv, w.w, a.w);
    }
    float mx = fmaxf(fmaxf(a.x, a.y), fmaxf(a.z, a.w));
    mx = fmaxf(mx, __shfl_xor(mx, 1));
    mx = fmaxf(mx, __shfl_xor(mx, 2));
    float sm = __expf(a.x - mx) + __expf(a.y - mx) + __expf(a.z - mx) + __expf(a.w - mx);
    sm += __shfl_xor(sm, 1);
    sm += __shfl_xor(sm, 2);
    float lse = mx + __logf(sm);
    int ng = nbase + node;
    if (ng < NN) {
        float4 r = make_float4(a.x - lse, a.y - lse, a.z - lse, a.w - lse);
        *(float4*)&out[(size_t)ng * 16 + cg * 4] = r;
    }
}

extern "C" void kernel_launch(void* const* d_in, const int* in_sizes, int n_in,
                              void* d_out, int out_size, void* d_ws, size_t ws_size,
                              hipStream_t stream) {
    const float* x      = (const float*)d_in[0];
    const int*   ei     = (const int*)d_in[1];
    const float* W_enc  = (const float*)d_in[2];
    const float* b_enc  = (const float*)d_in[3];
    const float* W_conv = (const float*)d_in[4];
    const float* b_conv = (const float*)d_in[5];
    const float* W_dec  = (const float*)d_in[6];
    const float* b_dec  = (const float*)d_in[7];
    const float* W_s    = (const float*)d_in[8];
    const float* b_s    = (const float*)d_in[9];
    const float* qv     = (const float*)d_in[10];
    const float* W_o    = (const float*)d_in[11];
    const float* b_o    = (const float*)d_in[12];
    float* out = (float*)d_out;

    char* ws = (char*)d_ws;
    size_t off = 0;
    auto alloc = [&](size_t bytes) -> char* {
        char* p = ws + off;
        off = (off + bytes + 255) & ~(size_t)255;
        return p;
    };
    int*   row_ofs = (int*)alloc((size_t)MM * (NN + 1) * 4);
    float* rs      = (float*)alloc((size_t)MM * NN * 4);
    int*   sorted  = (int*)alloc((size_t)MM * EE * 4);
    u64*   queues  = (u64*)alloc((size_t)MM * NBKT * QCAP * 8);
    int*   gcur    = (int*)alloc((size_t)MM * NBKT * 4);
    float* score   = (float*)alloc(64);
    u16*   wbe     = (u16*)alloc((size_t)MM * 2048 * 8 * 2);
    u16*   wbc     = (u16*)alloc((size_t)MM * 1024 * 8 * 2);
    u16*   wbd     = (u16*)alloc((size_t)MM * 512 * 8 * 2);
    u16*   wbs     = (u16*)alloc((size_t)1024 * 8 * 2);
    u8*    xw_buf  = (u8*)alloc((size_t)MM * XWN * 128);
    u16*   z_buf   = (u16*)alloc((size_t)MM * NN * 64 * 2);
    u16*   xb      = (u16*)alloc((size_t)NN * IND * 2);

    // node 1: xprep (+ zero gcur/score) — no memset nodes
    k_xprep<<<XCB + 46, 256, 0, stream>>>(x, W_enc, W_conv, W_dec, W_s,
                                          xb, wbe, wbc, wbd, wbs, gcur, score);

    dim3 gbkt(BBLK, MM);
    dim3 gcsr(NBKT, MM);
    k_bucket<<<gbkt, 256, 0, stream>>>(ei, queues, gcur);
    k_csr<<<gcsr, 512, 0, stream>>>(queues, gcur, row_ofs, rs, sorted);

    const int GB = (NN + 63) / 64;   // 782
    dim3 gmm(GB, MM);
    k_encconv<<<gmm, 256, 0, stream>>>(xb, wbe, b_enc, wbc, rs, xw_buf);
    k_gpost<<<gmm, 512, 0, stream>>>(sorted, row_ofs, rs, xw_buf,
                                     b_conv, wbd, b_dec, wbs, b_s, qv,
                                     z_buf, score);
    k_out<<<GB, 256, 0, stream>>>(z_buf, score, W_o, b_o, out);
}